// Round 6
// baseline (1187.862 us; speedup 1.0000x reference)
//
#include <hip/hip_runtime.h>
#include <hip/hip_bf16.h>

// Problem constants (match reference)
#define NN 100000
#define NE 3200000
#define F_IN 512
#define NHID 64
#define NCLS 40

// Radix-partition CSR build params
#define NB2 512   // row buckets
#define RPB2 196  // rows per bucket (512*196 = 100352 >= NN)
#define CHK 4096  // edges per chunk
#define NCH 782   // ceil(NE/CHK)
#define EPT 16    // edges per thread in P3 (CHK/256)
#define ECAP 7168 // emit LDS capacity (mean 6250, sigma 79 -> +11.6 sigma)
#define TOT (NB2 * NCH)  // 400,384 = 391 * 1024 exactly
#define NSB 391   // scan blocks

#define TPN 5     // threads per node in propagation (8 classes each)

// P4 combined-key counting sort: key = (row_local<<6) | (col>>11)
#define GCOL 64   // column groups per row (col granularity 2048 nodes)
#define CSH 11
#define NBIN (RPB2 * GCOL)  // 12544 = 256 * 49
#define SEG (NBIN / 256)    // 49 bins per thread in the scan

// degree-sort bins (descending degree)
#define DBIN 128

// bf16 helpers (exact up-convert; RNE down-convert)
__device__ __forceinline__ float bf2f(unsigned short u) {
  return __uint_as_float((unsigned)u << 16);
}
__device__ __forceinline__ unsigned short f2bf(float f) {
  unsigned u = __float_as_uint(f);
  u += 0x7FFFu + ((u >> 16) & 1u);  // round-to-nearest-even
  return (unsigned short)(u >> 16);
}
// packed-bf16 (uint = 2 classes) helpers
__device__ __forceinline__ float blo(unsigned u) {
  return __uint_as_float(u << 16);
}
__device__ __forceinline__ float bhi(unsigned u) {
  return __uint_as_float(u & 0xffff0000u);
}
__device__ __forceinline__ unsigned pk(float l, float h) {
  return (unsigned)f2bf(l) | ((unsigned)f2bf(h) << 16);
}

// ---------------------------------------------------------------------------
// GEMM1: H[N,64] = relu(F[N,512] @ W1[512,64] + b1)
// ---------------------------------------------------------------------------
__global__ __launch_bounds__(256) void gemm1_kernel(
    const float* __restrict__ F, const float* __restrict__ W1,
    const float* __restrict__ b1, float* __restrict__ H) {
  __shared__ float As[16][68];
  __shared__ float Bs[16][64];
  const int tid = threadIdx.x;
  const int m0 = blockIdx.x * 64;
  const int ty = tid >> 4;
  const int tx = tid & 15;
  const int lrowA = tid >> 2;
  const int lkA = (tid & 3) * 4;
  const int lkB = tid >> 4;
  const int lcolB = (tid & 15) * 4;
  const bool rowok = (m0 + lrowA) < NN;
  const int rclamp = rowok ? (m0 + lrowA) : (NN - 1);
  const float* Fb = F + (long)rclamp * F_IN + lkA;

  float acc[4][4] = {};
  for (int k0 = 0; k0 < F_IN; k0 += 16) {
    float4 fa = *(const float4*)(Fb + k0);
    if (!rowok) fa = make_float4(0.f, 0.f, 0.f, 0.f);
    float4 wb = *(const float4*)(W1 + (long)(k0 + lkB) * NHID + lcolB);
    __syncthreads();
    As[lkA + 0][lrowA] = fa.x;
    As[lkA + 1][lrowA] = fa.y;
    As[lkA + 2][lrowA] = fa.z;
    As[lkA + 3][lrowA] = fa.w;
    *(float4*)&Bs[lkB][lcolB] = wb;
    __syncthreads();
#pragma unroll
    for (int kk = 0; kk < 16; ++kk) {
      float4 a = *(const float4*)&As[kk][ty * 4];
      float4 b = *(const float4*)&Bs[kk][tx * 4];
      float av[4] = {a.x, a.y, a.z, a.w};
      float bv[4] = {b.x, b.y, b.z, b.w};
#pragma unroll
      for (int i = 0; i < 4; ++i)
#pragma unroll
        for (int j = 0; j < 4; ++j) acc[i][j] = fmaf(av[i], bv[j], acc[i][j]);
    }
  }
  float4 bb = *(const float4*)(b1 + tx * 4);
  float bv[4] = {bb.x, bb.y, bb.z, bb.w};
#pragma unroll
  for (int i = 0; i < 4; ++i) {
    int r = m0 + ty * 4 + i;
    if (r < NN) {
      float4 o;
      o.x = fmaxf(acc[i][0] + bv[0], 0.f);
      o.y = fmaxf(acc[i][1] + bv[1], 0.f);
      o.z = fmaxf(acc[i][2] + bv[2], 0.f);
      o.w = fmaxf(acc[i][3] + bv[3], 0.f);
      *(float4*)(H + (long)r * NHID + tx * 4) = o;
    }
  }
}

// ---------------------------------------------------------------------------
// GEMM2: X0b (bf16) = H @ W2 + b2.  (teleport term h consumed in bf16)
// ---------------------------------------------------------------------------
__global__ __launch_bounds__(256) void gemm2_kernel(
    const float* __restrict__ H, const float* __restrict__ W2,
    const float* __restrict__ b2, ushort4* __restrict__ X0b) {
  __shared__ float Ws[NHID * NCLS];
  __shared__ float bs[NCLS];
  const int tid = threadIdx.x;
  for (int i = tid; i < NHID * NCLS; i += 256) Ws[i] = W2[i];
  if (tid < NCLS) bs[tid] = b2[tid];
  __syncthreads();
  const int node = blockIdx.x * 256 + tid;
  if (node >= NN) return;
  float acc[NCLS];
#pragma unroll
  for (int j = 0; j < NCLS; ++j) acc[j] = bs[j];
  const float4* h4 = (const float4*)(H + (long)node * NHID);
#pragma unroll
  for (int kq = 0; kq < 16; ++kq) {
    float4 h = h4[kq];
    float hv[4] = {h.x, h.y, h.z, h.w};
#pragma unroll
    for (int u = 0; u < 4; ++u) {
      const int k = kq * 4 + u;
#pragma unroll
      for (int j = 0; j < NCLS; ++j)
        acc[j] = fmaf(hv[u], Ws[k * NCLS + j], acc[j]);
    }
  }
#pragma unroll
  for (int q = 0; q < 10; ++q) {
    X0b[node * 10 + q] = make_ushort4(f2bf(acc[q * 4]), f2bf(acc[q * 4 + 1]),
                                      f2bf(acc[q * 4 + 2]), f2bf(acc[q * 4 + 3]));
  }
}

// ---------------------------------------------------------------------------
// P1: per-chunk bucket histogram (LDS atomics, coalesced dump)
// ---------------------------------------------------------------------------
__global__ __launch_bounds__(256) void p1_count(const int* __restrict__ row,
                                                int* __restrict__ hist) {
  __shared__ int h[NB2];
  const int tid = threadIdx.x, blk = blockIdx.x;
  for (int i = tid; i < NB2; i += 256) h[i] = 0;
  __syncthreads();
  const int e0 = blk * CHK;
#pragma unroll
  for (int k = 0; k < EPT; ++k) {
    int e = e0 + k * 256 + tid;
    if (e < NE) atomicAdd(&h[row[e] / RPB2], 1);
  }
  __syncthreads();
  for (int i = tid; i < NB2; i += 256) hist[blk * NB2 + i] = h[i];
}

// ---------------------------------------------------------------------------
// P2 hierarchical scan over flat order f = b*NCH + blk (reads hist[blk][b]).
// ---------------------------------------------------------------------------
__global__ __launch_bounds__(1024) void p2a_scan(const int* __restrict__ hist,
                                                 int* __restrict__ base,
                                                 int* __restrict__ bsum) {
  __shared__ int sm[1024];
  const int t = threadIdx.x;
  const int f = blockIdx.x * 1024 + t;
  const int b = f / NCH, blk = f - b * NCH;
  const int v = hist[blk * NB2 + b];
  sm[t] = v;
  __syncthreads();
  for (int off = 1; off < 1024; off <<= 1) {
    int u = (t >= off) ? sm[t - off] : 0;
    __syncthreads();
    sm[t] += u;
    __syncthreads();
  }
  base[f] = sm[t] - v;
  if (t == 1023) bsum[blockIdx.x] = sm[t];
}

__global__ __launch_bounds__(512) void p2b_scan(const int* __restrict__ bsum,
                                                int* __restrict__ boff) {
  __shared__ int sm[512];
  const int t = threadIdx.x;
  const int v = (t < NSB) ? bsum[t] : 0;
  sm[t] = v;
  __syncthreads();
  for (int off = 1; off < 512; off <<= 1) {
    int u = (t >= off) ? sm[t - off] : 0;
    __syncthreads();
    sm[t] += u;
    __syncthreads();
  }
  if (t < NSB) boff[t] = sm[t] - v;
}

__global__ __launch_bounds__(1024) void p2c_add(int* __restrict__ base,
                                                const int* __restrict__ boff) {
  const int f = blockIdx.x * 1024 + threadIdx.x;
  base[f] += boff[blockIdx.x];
}

// ---------------------------------------------------------------------------
// P3: partition into 512 buckets; block-private contiguous global writes.
// staged.x = (col<<8) | row_local;  staged.y = ev bits
// ---------------------------------------------------------------------------
__global__ __launch_bounds__(256) void p3_scatter(
    const int* __restrict__ row, const int* __restrict__ col,
    const float* __restrict__ ev, const int* __restrict__ base,
    int2* __restrict__ staged) {
  __shared__ int h[NB2], lscan[NB2], lcur[NB2], gbase[NB2];
  __shared__ int tmp[256];
  __shared__ int2 pay[CHK];
  __shared__ unsigned short binof[CHK];
  const int tid = threadIdx.x, blk = blockIdx.x;
  for (int i = tid; i < NB2; i += 256) { h[i] = 0; lcur[i] = 0; }
  __syncthreads();
  const int e0 = blk * CHK;
  const int n = (NE - e0 < CHK) ? (NE - e0) : CHK;
  int eb[EPT], em[EPT], ee[EPT];
#pragma unroll
  for (int k = 0; k < EPT; ++k) {
    int e = e0 + k * 256 + tid;
    if (e < NE) {
      int r = row[e];
      int b = r / RPB2;
      eb[k] = b;
      em[k] = (col[e] << 8) | (r - b * RPB2);
      ee[k] = __float_as_int(ev[e]);
      atomicAdd(&h[b], 1);
    } else {
      eb[k] = -1;
    }
  }
  __syncthreads();
  int a = h[2 * tid], c = h[2 * tid + 1];
  tmp[tid] = a + c;
  __syncthreads();
  for (int off = 1; off < 256; off <<= 1) {
    int v = (tid >= off) ? tmp[tid - off] : 0;
    __syncthreads();
    tmp[tid] += v;
    __syncthreads();
  }
  int excl = tmp[tid] - (a + c);
  lscan[2 * tid] = excl;
  lscan[2 * tid + 1] = excl + a;
  gbase[2 * tid] = base[(2 * tid) * NCH + blk];
  gbase[2 * tid + 1] = base[(2 * tid + 1) * NCH + blk];
  __syncthreads();
#pragma unroll
  for (int k = 0; k < EPT; ++k) {
    if (eb[k] >= 0) {
      int b = eb[k];
      int p = lscan[b] + atomicAdd(&lcur[b], 1);
      pay[p] = make_int2(em[k], ee[k]);
      binof[p] = (unsigned short)b;
    }
  }
  __syncthreads();
  for (int j = tid; j < n; j += 256) {
    int b = binof[j];
    staged[gbase[b] + (j - lscan[b])] = pay[j];
  }
}

// ---------------------------------------------------------------------------
// P4: parallel counting sort by combined key (row_local, col>>11) in LDS.
// Exact row grouping (CSR) + coarse ascending column order within each row
// -> prop gathers sweep x in an L2-resident moving window.
// ---------------------------------------------------------------------------
__global__ __launch_bounds__(256) void p4_emit(
    const int* __restrict__ base, const int2* __restrict__ staged,
    int2* __restrict__ edges, int* __restrict__ rp) {
  __shared__ int bh[NBIN];      // 12544 bins: histogram -> starts -> cursors
  __shared__ int tsum[256];
  __shared__ int2 pay[ECAP];
  const int b = blockIdx.x, tid = threadIdx.x;
  const int s0 = base[b * NCH];
  const int s1 = (b == NB2 - 1) ? NE : base[(b + 1) * NCH];
  const int cnt = s1 - s0;
  for (int i = tid; i < NBIN; i += 256) bh[i] = 0;
  __syncthreads();
  // histogram over combined key
  for (int j = tid; j < cnt; j += 256) {
    int ex = staged[s0 + j].x;
    int rl = ex & 255;
    unsigned col = (unsigned)ex >> 8;
    atomicAdd(&bh[(rl << 6) | (col >> CSH)], 1);
  }
  __syncthreads();
  // exclusive scan over 12544 bins: 49 serial bins/thread + block scan
  int s = 0;
#pragma unroll
  for (int i = 0; i < SEG; ++i) {
    int v = bh[tid * SEG + i];
    bh[tid * SEG + i] = s;
    s += v;
  }
  tsum[tid] = s;
  __syncthreads();
  for (int off = 1; off < 256; off <<= 1) {
    int u = (tid >= off) ? tsum[tid - off] : 0;
    __syncthreads();
    tsum[tid] += u;
    __syncthreads();
  }
  const int add = (tid > 0) ? tsum[tid - 1] : 0;
#pragma unroll
  for (int i = 0; i < SEG; ++i) bh[tid * SEG + i] += add;
  __syncthreads();
  // rp from row-bin starts (before scatter mutates the cursors)
  if (tid < RPB2) {
    int r = b * RPB2 + tid;
    if (r <= NN) rp[r] = s0 + bh[tid << 6];
  }
  __syncthreads();
  // scatter via per-bin cursors
  if (cnt <= ECAP) {
    for (int j = tid; j < cnt; j += 256) {
      int2 ed = staged[s0 + j];
      int rl = ed.x & 255;
      unsigned col = (unsigned)ed.x >> 8;
      int p = atomicAdd(&bh[(rl << 6) | (col >> CSH)], 1);
      pay[p] = make_int2((int)col, ed.y);
    }
    __syncthreads();
    for (int j = tid; j < cnt; j += 256) edges[s0 + j] = pay[j];
  } else {
    for (int j = tid; j < cnt; j += 256) {
      int2 ed = staged[s0 + j];
      int rl = ed.x & 255;
      unsigned col = (unsigned)ed.x >> 8;
      int p = atomicAdd(&bh[(rl << 6) | (col >> CSH)], 1);
      edges[s0 + p] = make_int2((int)col, ed.y);
    }
  }
}

// ---------------------------------------------------------------------------
// Degree-sorted node permutation (descending): waves become degree-
// homogeneous -> no masked-lane waste; co-resident blocks sweep the sorted
// column space at equal rates -> tighter machine-wide L2 window.
// ---------------------------------------------------------------------------
__global__ __launch_bounds__(256) void d1_hist(const int* __restrict__ rp,
                                               int* __restrict__ dh) {
  __shared__ int h[DBIN];
  const int tid = threadIdx.x;
  if (tid < DBIN) h[tid] = 0;
  __syncthreads();
  const int n = blockIdx.x * 256 + tid;
  if (n < NN) {
    int d = rp[n + 1] - rp[n];
    d = d > (DBIN - 1) ? (DBIN - 1) : d;
    atomicAdd(&h[(DBIN - 1) - d], 1);
  }
  __syncthreads();
  if (tid < DBIN && h[tid]) atomicAdd(&dh[tid], h[tid]);
}

__global__ __launch_bounds__(DBIN) void d2_scan(const int* __restrict__ dh,
                                                int* __restrict__ doff) {
  __shared__ int sm[DBIN];
  const int t = threadIdx.x;
  const int v = dh[t];
  sm[t] = v;
  __syncthreads();
  for (int off = 1; off < DBIN; off <<= 1) {
    int u = (t >= off) ? sm[t - off] : 0;
    __syncthreads();
    sm[t] += u;
    __syncthreads();
  }
  doff[t] = sm[t] - v;
}

__global__ __launch_bounds__(256) void d3_scat(const int* __restrict__ rp,
                                               int* __restrict__ doff,
                                               int* __restrict__ perm) {
  const int n = blockIdx.x * 256 + threadIdx.x;
  if (n < NN) {
    int d = rp[n + 1] - rp[n];
    d = d > (DBIN - 1) ? (DBIN - 1) : d;
    int p = atomicAdd(&doff[(DBIN - 1) - d], 1);
    perm[p] = n;
  }
}

// ---------------------------------------------------------------------------
// Propagation (bf16 x): x_out = 0.9*(A x_in) + 0.1*h.
// TPN=5 threads/node, each owns 8 classes (one 16 B uint4 of packed bf16).
// Nodes assigned via degree-sorted perm; 4-edge unrolled inner loop keeps
// 4 independent gathers in flight.
// ---------------------------------------------------------------------------
#define FMA8(v, xb)                                              \
  a0 = fmaf(v, blo(xb.x), a0); a1 = fmaf(v, bhi(xb.x), a1);      \
  a2 = fmaf(v, blo(xb.y), a2); a3 = fmaf(v, bhi(xb.y), a3);      \
  a4 = fmaf(v, blo(xb.z), a4); a5 = fmaf(v, bhi(xb.z), a5);      \
  a6 = fmaf(v, blo(xb.w), a6); a7 = fmaf(v, bhi(xb.w), a7);

__global__ __launch_bounds__(256) void prop_kernel_bf16(
    const uint4* __restrict__ xin, uint4* __restrict__ xout,
    const uint4* __restrict__ hb, const int2* __restrict__ edges,
    const int* __restrict__ rp, const int* __restrict__ perm) {
  const int t = blockIdx.x * 256 + threadIdx.x;
  const int i = t / TPN;
  if (i >= NN) return;
  const int g = t - i * TPN;  // class-group 0..4 (classes 8g..8g+7)
  const int nid = perm[i];
  const int e0 = rp[nid], e1 = rp[nid + 1];
  float a0 = 0.f, a1 = 0.f, a2 = 0.f, a3 = 0.f;
  float a4 = 0.f, a5 = 0.f, a6 = 0.f, a7 = 0.f;
  int e = e0;
  // prologue: align e to even for int4 edge-pair loads
  if ((e & 1) && e < e1) {
    int2 ed = edges[e];
    float v = __int_as_float(ed.y);
    uint4 xb = xin[ed.x * TPN + g];
    FMA8(v, xb);
    ++e;
  }
  const int4* edges2 = (const int4*)edges;
  while (e + 4 <= e1) {
    int4 ea = edges2[e >> 1];
    int4 eb = edges2[(e >> 1) + 1];
    float v0 = __int_as_float(ea.y);
    float v1 = __int_as_float(ea.w);
    float v2 = __int_as_float(eb.y);
    float v3 = __int_as_float(eb.w);
    uint4 xb0 = xin[ea.x * TPN + g];
    uint4 xb1 = xin[ea.z * TPN + g];
    uint4 xb2 = xin[eb.x * TPN + g];
    uint4 xb3 = xin[eb.z * TPN + g];
    FMA8(v0, xb0);
    FMA8(v1, xb1);
    FMA8(v2, xb2);
    FMA8(v3, xb3);
    e += 4;
  }
  if (e + 2 <= e1) {
    int4 ep = edges2[e >> 1];
    float v0 = __int_as_float(ep.y);
    float v1 = __int_as_float(ep.w);
    uint4 xb0 = xin[ep.x * TPN + g];
    uint4 xb1 = xin[ep.z * TPN + g];
    FMA8(v0, xb0);
    FMA8(v1, xb1);
    e += 2;
  }
  if (e < e1) {
    int2 ed = edges[e];
    float v = __int_as_float(ed.y);
    uint4 xb = xin[ed.x * TPN + g];
    FMA8(v, xb);
  }
  uint4 hh = hb[nid * TPN + g];
  uint4 r;
  r.x = pk(fmaf(0.9f, a0, 0.1f * blo(hh.x)), fmaf(0.9f, a1, 0.1f * bhi(hh.x)));
  r.y = pk(fmaf(0.9f, a2, 0.1f * blo(hh.y)), fmaf(0.9f, a3, 0.1f * bhi(hh.y)));
  r.z = pk(fmaf(0.9f, a4, 0.1f * blo(hh.z)), fmaf(0.9f, a5, 0.1f * bhi(hh.z)));
  r.w = pk(fmaf(0.9f, a6, 0.1f * blo(hh.w)), fmaf(0.9f, a7, 0.1f * bhi(hh.w)));
  xout[nid * TPN + g] = r;
}

// ---------------------------------------------------------------------------
// log_softmax over 40 classes (bf16 in, fp32 out), one thread per node
// ---------------------------------------------------------------------------
__global__ __launch_bounds__(256) void logsm_kernel(
    const ushort4* __restrict__ X, float* __restrict__ out) {
  const int node = blockIdx.x * 256 + threadIdx.x;
  if (node >= NN) return;
  float v[NCLS];
#pragma unroll
  for (int q = 0; q < 10; ++q) {
    ushort4 a = X[node * 10 + q];
    v[q * 4] = bf2f(a.x);
    v[q * 4 + 1] = bf2f(a.y);
    v[q * 4 + 2] = bf2f(a.z);
    v[q * 4 + 3] = bf2f(a.w);
  }
  float m = v[0];
#pragma unroll
  for (int j = 1; j < NCLS; ++j) m = fmaxf(m, v[j]);
  float s = 0.f;
#pragma unroll
  for (int j = 0; j < NCLS; ++j) s += expf(v[j] - m);
  const float l = m + logf(s);
  float4* o4 = (float4*)(out + (long)node * NCLS);
#pragma unroll
  for (int q = 0; q < 10; ++q)
    o4[q] = make_float4(v[q * 4] - l, v[q * 4 + 1] - l, v[q * 4 + 2] - l,
                        v[q * 4 + 3] - l);
}

// ---------------------------------------------------------------------------
// Launch
// ---------------------------------------------------------------------------
extern "C" void kernel_launch(void* const* d_in, const int* in_sizes, int n_in,
                              void* d_out, int out_size, void* d_ws,
                              size_t ws_size, hipStream_t stream) {
  const float* F = (const float*)d_in[0];
  const int* EI = (const int*)d_in[1];
  const float* EV = (const float*)d_in[2];
  const float* W1 = (const float*)d_in[3];
  const float* b1 = (const float*)d_in[4];
  const float* W2 = (const float*)d_in[5];
  const float* b2 = (const float*)d_in[6];
  float* out = (float*)d_out;
  char* ws = (char*)d_ws;

  // ws layout, phase-aliased:
  //   build:  STAGED [0,25.6M)  HIST@42M  BASE@43.7M  BSUM/BOFF@45.4M
  //           EDG [48M,73.6M)  RP@73.6M  PERM@74.2M  DHIST/DOFF@74.8M
  //   gemms:  H [16M,41.6M)  X0b@76M (bf16)
  //   prop :  X0b (=h AND x_0, bf16)  XAb/XBb bf16 @84/92M  EDG, RP, PERM
  int2* STAGED = (int2*)(ws + 0);
  float* H = (float*)(ws + 16000000);
  int* HIST = (int*)(ws + 42000000);
  int* BASE = (int*)(ws + 43700000);
  int* BSUM = (int*)(ws + 45400000);
  int* BOFF = (int*)(ws + 45402048);
  int2* EDG = (int2*)(ws + 48000000);
  int* RP = (int*)(ws + 73600000);
  int* PERM = (int*)(ws + 74200000);
  int* DHIST = (int*)(ws + 74800000);
  int* DOFF = (int*)(ws + 74801024);
  uint4* X0b = (uint4*)(ws + 76000000);  // NN*40 bf16 = 8 MB
  uint4* XAb = (uint4*)(ws + 84000000);
  uint4* XBb = (uint4*)(ws + 92000000);  // ends at 100 MB

  const int* ROW = EI;       // edge_index[0]
  const int* COL = EI + NE;  // edge_index[1]

  // --- CSR build ---
  p1_count<<<NCH, 256, 0, stream>>>(ROW, HIST);
  p2a_scan<<<NSB, 1024, 0, stream>>>(HIST, BASE, BSUM);
  p2b_scan<<<1, 512, 0, stream>>>(BSUM, BOFF);
  p2c_add<<<NSB, 1024, 0, stream>>>(BASE, BOFF);
  p3_scatter<<<NCH, 256, 0, stream>>>(ROW, COL, EV, BASE, STAGED);
  p4_emit<<<NB2, 256, 0, stream>>>(BASE, STAGED, EDG, RP);

  // --- degree-sorted node permutation ---
  hipMemsetAsync(DHIST, 0, DBIN * sizeof(int), stream);
  d1_hist<<<(NN + 255) / 256, 256, 0, stream>>>(RP, DHIST);
  d2_scan<<<1, DBIN, 0, stream>>>(DHIST, DOFF);
  d3_scat<<<(NN + 255) / 256, 256, 0, stream>>>(RP, DOFF, PERM);

  // --- MLP ---
  gemm1_kernel<<<(NN + 63) / 64, 256, 0, stream>>>(F, W1, b1, H);
  gemm2_kernel<<<(NN + 255) / 256, 256, 0, stream>>>(H, W2, b2,
                                                     (ushort4*)X0b);

  // --- propagation (bf16 x, bf16 h) ---
  const int tgrid = (NN * TPN + 255) / 256;
  const uint4* cur_in = X0b;
  uint4* bufs[2] = {XAb, XBb};
  for (int it = 0; it < 10; ++it) {
    uint4* o = bufs[it & 1];
    prop_kernel_bf16<<<tgrid, 256, 0, stream>>>(cur_in, o, X0b, EDG, RP, PERM);
    cur_in = o;
  }
  logsm_kernel<<<(NN + 255) / 256, 256, 0, stream>>>((const ushort4*)cur_in,
                                                     out);
}

// Round 7
// 964.051 us; speedup vs baseline: 1.2322x; 1.2322x over previous
//
#include <hip/hip_runtime.h>
#include <hip/hip_bf16.h>

// Problem constants (match reference)
#define NN 100000
#define NE 3200000
#define F_IN 512
#define NHID 64
#define NCLS 40

// Radix-partition CSR build params
#define NB2 512   // row buckets
#define RPB2 196  // rows per bucket (512*196 = 100352 >= NN)
#define CHK 4096  // edges per chunk
#define NCH 782   // ceil(NE/CHK)
#define EPT 16    // edges per thread in P3 (CHK/256)
#define ECAP 7168 // emit LDS capacity (mean 6250, sigma 79 -> +11.6 sigma)
#define TOT (NB2 * NCH)  // 400,384 = 391 * 1024 exactly
#define NSB 391   // scan blocks

#define TPN 5     // threads per node in propagation (8 classes each)

// P4 combined-key counting sort: key = (row_local<<6) | (col>>11)
#define GCOL 64   // column groups per row (col granularity 2048 nodes)
#define CSH 11
#define NBIN (RPB2 * GCOL)  // 12544 = 256 * 49
#define SEG (NBIN / 256)    // 49 bins per thread in the scan

// prop column tiles: 8 tiles x 16384 cols (= 8 bins of 2048)
#define NTILE 8

// bf16 helpers (exact up-convert; RNE down-convert)
__device__ __forceinline__ float bf2f(unsigned short u) {
  return __uint_as_float((unsigned)u << 16);
}
__device__ __forceinline__ unsigned short f2bf(float f) {
  unsigned u = __float_as_uint(f);
  u += 0x7FFFu + ((u >> 16) & 1u);  // round-to-nearest-even
  return (unsigned short)(u >> 16);
}
// packed-bf16 (uint = 2 classes) helpers
__device__ __forceinline__ float blo(unsigned u) {
  return __uint_as_float(u << 16);
}
__device__ __forceinline__ float bhi(unsigned u) {
  return __uint_as_float(u & 0xffff0000u);
}
__device__ __forceinline__ unsigned pk(float l, float h) {
  return (unsigned)f2bf(l) | ((unsigned)f2bf(h) << 16);
}

// ---------------------------------------------------------------------------
// GEMM1: H[N,64] = relu(F[N,512] @ W1[512,64] + b1)
// ---------------------------------------------------------------------------
__global__ __launch_bounds__(256) void gemm1_kernel(
    const float* __restrict__ F, const float* __restrict__ W1,
    const float* __restrict__ b1, float* __restrict__ H) {
  __shared__ float As[16][68];
  __shared__ float Bs[16][64];
  const int tid = threadIdx.x;
  const int m0 = blockIdx.x * 64;
  const int ty = tid >> 4;
  const int tx = tid & 15;
  const int lrowA = tid >> 2;
  const int lkA = (tid & 3) * 4;
  const int lkB = tid >> 4;
  const int lcolB = (tid & 15) * 4;
  const bool rowok = (m0 + lrowA) < NN;
  const int rclamp = rowok ? (m0 + lrowA) : (NN - 1);
  const float* Fb = F + (long)rclamp * F_IN + lkA;

  float acc[4][4] = {};
  for (int k0 = 0; k0 < F_IN; k0 += 16) {
    float4 fa = *(const float4*)(Fb + k0);
    if (!rowok) fa = make_float4(0.f, 0.f, 0.f, 0.f);
    float4 wb = *(const float4*)(W1 + (long)(k0 + lkB) * NHID + lcolB);
    __syncthreads();
    As[lkA + 0][lrowA] = fa.x;
    As[lkA + 1][lrowA] = fa.y;
    As[lkA + 2][lrowA] = fa.z;
    As[lkA + 3][lrowA] = fa.w;
    *(float4*)&Bs[lkB][lcolB] = wb;
    __syncthreads();
#pragma unroll
    for (int kk = 0; kk < 16; ++kk) {
      float4 a = *(const float4*)&As[kk][ty * 4];
      float4 b = *(const float4*)&Bs[kk][tx * 4];
      float av[4] = {a.x, a.y, a.z, a.w};
      float bv[4] = {b.x, b.y, b.z, b.w};
#pragma unroll
      for (int i = 0; i < 4; ++i)
#pragma unroll
        for (int j = 0; j < 4; ++j) acc[i][j] = fmaf(av[i], bv[j], acc[i][j]);
    }
  }
  float4 bb = *(const float4*)(b1 + tx * 4);
  float bv[4] = {bb.x, bb.y, bb.z, bb.w};
#pragma unroll
  for (int i = 0; i < 4; ++i) {
    int r = m0 + ty * 4 + i;
    if (r < NN) {
      float4 o;
      o.x = fmaxf(acc[i][0] + bv[0], 0.f);
      o.y = fmaxf(acc[i][1] + bv[1], 0.f);
      o.z = fmaxf(acc[i][2] + bv[2], 0.f);
      o.w = fmaxf(acc[i][3] + bv[3], 0.f);
      *(float4*)(H + (long)r * NHID + tx * 4) = o;
    }
  }
}

// ---------------------------------------------------------------------------
// GEMM2: X0b (bf16) = H @ W2 + b2.  (teleport term h consumed in bf16)
// ---------------------------------------------------------------------------
__global__ __launch_bounds__(256) void gemm2_kernel(
    const float* __restrict__ H, const float* __restrict__ W2,
    const float* __restrict__ b2, ushort4* __restrict__ X0b) {
  __shared__ float Ws[NHID * NCLS];
  __shared__ float bs[NCLS];
  const int tid = threadIdx.x;
  for (int i = tid; i < NHID * NCLS; i += 256) Ws[i] = W2[i];
  if (tid < NCLS) bs[tid] = b2[tid];
  __syncthreads();
  const int node = blockIdx.x * 256 + tid;
  if (node >= NN) return;
  float acc[NCLS];
#pragma unroll
  for (int j = 0; j < NCLS; ++j) acc[j] = bs[j];
  const float4* h4 = (const float4*)(H + (long)node * NHID);
#pragma unroll
  for (int kq = 0; kq < 16; ++kq) {
    float4 h = h4[kq];
    float hv[4] = {h.x, h.y, h.z, h.w};
#pragma unroll
    for (int u = 0; u < 4; ++u) {
      const int k = kq * 4 + u;
#pragma unroll
      for (int j = 0; j < NCLS; ++j)
        acc[j] = fmaf(hv[u], Ws[k * NCLS + j], acc[j]);
    }
  }
#pragma unroll
  for (int q = 0; q < 10; ++q) {
    X0b[node * 10 + q] = make_ushort4(f2bf(acc[q * 4]), f2bf(acc[q * 4 + 1]),
                                      f2bf(acc[q * 4 + 2]), f2bf(acc[q * 4 + 3]));
  }
}

// ---------------------------------------------------------------------------
// P1: per-chunk bucket histogram (LDS atomics, coalesced dump)
// ---------------------------------------------------------------------------
__global__ __launch_bounds__(256) void p1_count(const int* __restrict__ row,
                                                int* __restrict__ hist) {
  __shared__ int h[NB2];
  const int tid = threadIdx.x, blk = blockIdx.x;
  for (int i = tid; i < NB2; i += 256) h[i] = 0;
  __syncthreads();
  const int e0 = blk * CHK;
#pragma unroll
  for (int k = 0; k < EPT; ++k) {
    int e = e0 + k * 256 + tid;
    if (e < NE) atomicAdd(&h[row[e] / RPB2], 1);
  }
  __syncthreads();
  for (int i = tid; i < NB2; i += 256) hist[blk * NB2 + i] = h[i];
}

// ---------------------------------------------------------------------------
// P2 hierarchical scan over flat order f = b*NCH + blk (reads hist[blk][b]).
// ---------------------------------------------------------------------------
__global__ __launch_bounds__(1024) void p2a_scan(const int* __restrict__ hist,
                                                 int* __restrict__ base,
                                                 int* __restrict__ bsum) {
  __shared__ int sm[1024];
  const int t = threadIdx.x;
  const int f = blockIdx.x * 1024 + t;
  const int b = f / NCH, blk = f - b * NCH;
  const int v = hist[blk * NB2 + b];
  sm[t] = v;
  __syncthreads();
  for (int off = 1; off < 1024; off <<= 1) {
    int u = (t >= off) ? sm[t - off] : 0;
    __syncthreads();
    sm[t] += u;
    __syncthreads();
  }
  base[f] = sm[t] - v;
  if (t == 1023) bsum[blockIdx.x] = sm[t];
}

__global__ __launch_bounds__(512) void p2b_scan(const int* __restrict__ bsum,
                                                int* __restrict__ boff) {
  __shared__ int sm[512];
  const int t = threadIdx.x;
  const int v = (t < NSB) ? bsum[t] : 0;
  sm[t] = v;
  __syncthreads();
  for (int off = 1; off < 512; off <<= 1) {
    int u = (t >= off) ? sm[t - off] : 0;
    __syncthreads();
    sm[t] += u;
    __syncthreads();
  }
  if (t < NSB) boff[t] = sm[t] - v;
}

__global__ __launch_bounds__(1024) void p2c_add(int* __restrict__ base,
                                                const int* __restrict__ boff) {
  const int f = blockIdx.x * 1024 + threadIdx.x;
  base[f] += boff[blockIdx.x];
}

// ---------------------------------------------------------------------------
// P3: partition into 512 buckets; block-private contiguous global writes.
// staged.x = (col<<8) | row_local;  staged.y = ev bits
// ---------------------------------------------------------------------------
__global__ __launch_bounds__(256) void p3_scatter(
    const int* __restrict__ row, const int* __restrict__ col,
    const float* __restrict__ ev, const int* __restrict__ base,
    int2* __restrict__ staged) {
  __shared__ int h[NB2], lscan[NB2], lcur[NB2], gbase[NB2];
  __shared__ int tmp[256];
  __shared__ int2 pay[CHK];
  __shared__ unsigned short binof[CHK];
  const int tid = threadIdx.x, blk = blockIdx.x;
  for (int i = tid; i < NB2; i += 256) { h[i] = 0; lcur[i] = 0; }
  __syncthreads();
  const int e0 = blk * CHK;
  const int n = (NE - e0 < CHK) ? (NE - e0) : CHK;
  int eb[EPT], em[EPT], ee[EPT];
#pragma unroll
  for (int k = 0; k < EPT; ++k) {
    int e = e0 + k * 256 + tid;
    if (e < NE) {
      int r = row[e];
      int b = r / RPB2;
      eb[k] = b;
      em[k] = (col[e] << 8) | (r - b * RPB2);
      ee[k] = __float_as_int(ev[e]);
      atomicAdd(&h[b], 1);
    } else {
      eb[k] = -1;
    }
  }
  __syncthreads();
  int a = h[2 * tid], c = h[2 * tid + 1];
  tmp[tid] = a + c;
  __syncthreads();
  for (int off = 1; off < 256; off <<= 1) {
    int v = (tid >= off) ? tmp[tid - off] : 0;
    __syncthreads();
    tmp[tid] += v;
    __syncthreads();
  }
  int excl = tmp[tid] - (a + c);
  lscan[2 * tid] = excl;
  lscan[2 * tid + 1] = excl + a;
  gbase[2 * tid] = base[(2 * tid) * NCH + blk];
  gbase[2 * tid + 1] = base[(2 * tid + 1) * NCH + blk];
  __syncthreads();
#pragma unroll
  for (int k = 0; k < EPT; ++k) {
    if (eb[k] >= 0) {
      int b = eb[k];
      int p = lscan[b] + atomicAdd(&lcur[b], 1);
      pay[p] = make_int2(em[k], ee[k]);
      binof[p] = (unsigned short)b;
    }
  }
  __syncthreads();
  for (int j = tid; j < n; j += 256) {
    int b = binof[j];
    staged[gbase[b] + (j - lscan[b])] = pay[j];
  }
}

// ---------------------------------------------------------------------------
// P4: parallel counting sort by combined key (row_local, col>>11) in LDS.
// Exact row grouping (CSR) + coarse ascending column order within each row.
// Additionally emits RP8[row][t]: per-row start of column-tile t
// (tile = 16384 cols = 8 bins), used by prop for rate-synced tile pacing.
// ---------------------------------------------------------------------------
__global__ __launch_bounds__(256) void p4_emit(
    const int* __restrict__ base, const int2* __restrict__ staged,
    int2* __restrict__ edges, int* __restrict__ rp, int* __restrict__ rp8) {
  __shared__ int bh[NBIN];      // 12544 bins: histogram -> starts -> cursors
  __shared__ int tsum[256];
  __shared__ int2 pay[ECAP];
  const int b = blockIdx.x, tid = threadIdx.x;
  const int s0 = base[b * NCH];
  const int s1 = (b == NB2 - 1) ? NE : base[(b + 1) * NCH];
  const int cnt = s1 - s0;
  for (int i = tid; i < NBIN; i += 256) bh[i] = 0;
  __syncthreads();
  // histogram over combined key
  for (int j = tid; j < cnt; j += 256) {
    int ex = staged[s0 + j].x;
    int rl = ex & 255;
    unsigned col = (unsigned)ex >> 8;
    atomicAdd(&bh[(rl << 6) | (col >> CSH)], 1);
  }
  __syncthreads();
  // exclusive scan over 12544 bins: 49 serial bins/thread + block scan
  int s = 0;
#pragma unroll
  for (int i = 0; i < SEG; ++i) {
    int v = bh[tid * SEG + i];
    bh[tid * SEG + i] = s;
    s += v;
  }
  tsum[tid] = s;
  __syncthreads();
  for (int off = 1; off < 256; off <<= 1) {
    int u = (tid >= off) ? tsum[tid - off] : 0;
    __syncthreads();
    tsum[tid] += u;
    __syncthreads();
  }
  const int add = (tid > 0) ? tsum[tid - 1] : 0;
#pragma unroll
  for (int i = 0; i < SEG; ++i) bh[tid * SEG + i] += add;
  __syncthreads();
  // rp + per-tile starts from bin starts (before scatter mutates cursors)
  if (tid < RPB2) {
    int r = b * RPB2 + tid;
    if (r <= NN) rp[r] = s0 + bh[tid << 6];
    if (r < NN) {
#pragma unroll
      for (int t = 0; t < NTILE; ++t)
        rp8[r * NTILE + t] = s0 + bh[(tid << 6) | (t << 3)];
    }
  }
  __syncthreads();
  // scatter via per-bin cursors
  if (cnt <= ECAP) {
    for (int j = tid; j < cnt; j += 256) {
      int2 ed = staged[s0 + j];
      int rl = ed.x & 255;
      unsigned col = (unsigned)ed.x >> 8;
      int p = atomicAdd(&bh[(rl << 6) | (col >> CSH)], 1);
      pay[p] = make_int2((int)col, ed.y);
    }
    __syncthreads();
    for (int j = tid; j < cnt; j += 256) edges[s0 + j] = pay[j];
  } else {
    for (int j = tid; j < cnt; j += 256) {
      int2 ed = staged[s0 + j];
      int rl = ed.x & 255;
      unsigned col = (unsigned)ed.x >> 8;
      int p = atomicAdd(&bh[(rl << 6) | (col >> CSH)], 1);
      edges[s0 + p] = make_int2((int)col, ed.y);
    }
  }
}

// ---------------------------------------------------------------------------
// Propagation (bf16 x): x_out = 0.9*(A x_in) + 0.1*h.
// TPN=5 threads/node, each owns 8 classes (one 16 B uint4 of packed bf16).
// Column-tile paced: outer loop over 8 global column tiles (16384 cols =
// 1.3 MB of x each). Every row processes tile t at the same loop depth
// regardless of degree -> the machine-wide gather window is one tile,
// resident in each XCD's 4 MiB L2.
// ---------------------------------------------------------------------------
#define FMA8(v, xb)                                              \
  a0 = fmaf(v, blo(xb.x), a0); a1 = fmaf(v, bhi(xb.x), a1);      \
  a2 = fmaf(v, blo(xb.y), a2); a3 = fmaf(v, bhi(xb.y), a3);      \
  a4 = fmaf(v, blo(xb.z), a4); a5 = fmaf(v, bhi(xb.z), a5);      \
  a6 = fmaf(v, blo(xb.w), a6); a7 = fmaf(v, bhi(xb.w), a7);

__global__ __launch_bounds__(256) void prop_kernel_bf16(
    const uint4* __restrict__ xin, uint4* __restrict__ xout,
    const uint4* __restrict__ hb, const int2* __restrict__ edges,
    const int* __restrict__ rp, const int4* __restrict__ rp8v) {
  const int t = blockIdx.x * 256 + threadIdx.x;
  const int node = t / TPN;
  if (node >= NN) return;
  const int g = t - node * TPN;  // class-group 0..4 (classes 8g..8g+7)
  const int e1 = rp[node + 1];
  const int4 ra = rp8v[node * 2];      // tile starts 0..3
  const int4 rb = rp8v[node * 2 + 1];  // tile starts 4..7
  int stops[NTILE];
  stops[0] = ra.y; stops[1] = ra.z; stops[2] = ra.w; stops[3] = rb.x;
  stops[4] = rb.y; stops[5] = rb.z; stops[6] = rb.w; stops[7] = e1;
  float a0 = 0.f, a1 = 0.f, a2 = 0.f, a3 = 0.f;
  float a4 = 0.f, a5 = 0.f, a6 = 0.f, a7 = 0.f;
  int e = ra.x;  // == rp[node]
#pragma unroll
  for (int tt = 0; tt < NTILE; ++tt) {
    const int estop = stops[tt];
    while (e + 4 <= estop) {
      int2 d0 = edges[e], d1 = edges[e + 1], d2 = edges[e + 2],
           d3 = edges[e + 3];
      uint4 x0 = xin[d0.x * TPN + g];
      uint4 x1 = xin[d1.x * TPN + g];
      uint4 x2 = xin[d2.x * TPN + g];
      uint4 x3 = xin[d3.x * TPN + g];
      float v0 = __int_as_float(d0.y), v1 = __int_as_float(d1.y);
      float v2 = __int_as_float(d2.y), v3 = __int_as_float(d3.y);
      FMA8(v0, x0);
      FMA8(v1, x1);
      FMA8(v2, x2);
      FMA8(v3, x3);
      e += 4;
    }
    if (e + 2 <= estop) {
      int2 d0 = edges[e], d1 = edges[e + 1];
      uint4 x0 = xin[d0.x * TPN + g];
      uint4 x1 = xin[d1.x * TPN + g];
      float v0 = __int_as_float(d0.y), v1 = __int_as_float(d1.y);
      FMA8(v0, x0);
      FMA8(v1, x1);
      e += 2;
    }
    if (e < estop) {
      int2 d0 = edges[e];
      uint4 x0 = xin[d0.x * TPN + g];
      float v0 = __int_as_float(d0.y);
      FMA8(v0, x0);
      ++e;
    }
  }
  uint4 hh = hb[node * TPN + g];
  uint4 r;
  r.x = pk(fmaf(0.9f, a0, 0.1f * blo(hh.x)), fmaf(0.9f, a1, 0.1f * bhi(hh.x)));
  r.y = pk(fmaf(0.9f, a2, 0.1f * blo(hh.y)), fmaf(0.9f, a3, 0.1f * bhi(hh.y)));
  r.z = pk(fmaf(0.9f, a4, 0.1f * blo(hh.z)), fmaf(0.9f, a5, 0.1f * bhi(hh.z)));
  r.w = pk(fmaf(0.9f, a6, 0.1f * blo(hh.w)), fmaf(0.9f, a7, 0.1f * bhi(hh.w)));
  xout[node * TPN + g] = r;
}

// ---------------------------------------------------------------------------
// log_softmax over 40 classes (bf16 in, fp32 out), one thread per node
// ---------------------------------------------------------------------------
__global__ __launch_bounds__(256) void logsm_kernel(
    const ushort4* __restrict__ X, float* __restrict__ out) {
  const int node = blockIdx.x * 256 + threadIdx.x;
  if (node >= NN) return;
  float v[NCLS];
#pragma unroll
  for (int q = 0; q < 10; ++q) {
    ushort4 a = X[node * 10 + q];
    v[q * 4] = bf2f(a.x);
    v[q * 4 + 1] = bf2f(a.y);
    v[q * 4 + 2] = bf2f(a.z);
    v[q * 4 + 3] = bf2f(a.w);
  }
  float m = v[0];
#pragma unroll
  for (int j = 1; j < NCLS; ++j) m = fmaxf(m, v[j]);
  float s = 0.f;
#pragma unroll
  for (int j = 0; j < NCLS; ++j) s += expf(v[j] - m);
  const float l = m + logf(s);
  float4* o4 = (float4*)(out + (long)node * NCLS);
#pragma unroll
  for (int q = 0; q < 10; ++q)
    o4[q] = make_float4(v[q * 4] - l, v[q * 4 + 1] - l, v[q * 4 + 2] - l,
                        v[q * 4 + 3] - l);
}

// ---------------------------------------------------------------------------
// Launch
// ---------------------------------------------------------------------------
extern "C" void kernel_launch(void* const* d_in, const int* in_sizes, int n_in,
                              void* d_out, int out_size, void* d_ws,
                              size_t ws_size, hipStream_t stream) {
  const float* F = (const float*)d_in[0];
  const int* EI = (const int*)d_in[1];
  const float* EV = (const float*)d_in[2];
  const float* W1 = (const float*)d_in[3];
  const float* b1 = (const float*)d_in[4];
  const float* W2 = (const float*)d_in[5];
  const float* b2 = (const float*)d_in[6];
  float* out = (float*)d_out;
  char* ws = (char*)d_ws;

  // ws layout, phase-aliased:
  //   build:  STAGED [0,25.6M)  HIST@42M  BASE@43.7M  BSUM/BOFF@45.4M
  //           EDG [48M,73.6M)  RP@73.6M  RP8@74.4M(3.2M)
  //   gemms:  H [16M,41.6M)  X0b@78M (bf16)
  //   prop :  X0b (=h AND x_0, bf16)  XAb/XBb bf16 @86.4/94.8M  EDG, RP, RP8
  int2* STAGED = (int2*)(ws + 0);
  float* H = (float*)(ws + 16000000);
  int* HIST = (int*)(ws + 42000000);
  int* BASE = (int*)(ws + 43700000);
  int* BSUM = (int*)(ws + 45400000);
  int* BOFF = (int*)(ws + 45402048);
  int2* EDG = (int2*)(ws + 48000000);
  int* RP = (int*)(ws + 73600000);
  int* RP8 = (int*)(ws + 74400000);      // NN*8 ints = 3.2 MB
  uint4* X0b = (uint4*)(ws + 78000000);  // NN*40 bf16 = 8 MB
  uint4* XAb = (uint4*)(ws + 86400000);
  uint4* XBb = (uint4*)(ws + 94800000);  // ends at 103.2 MB

  const int* ROW = EI;       // edge_index[0]
  const int* COL = EI + NE;  // edge_index[1]

  // --- CSR build ---
  p1_count<<<NCH, 256, 0, stream>>>(ROW, HIST);
  p2a_scan<<<NSB, 1024, 0, stream>>>(HIST, BASE, BSUM);
  p2b_scan<<<1, 512, 0, stream>>>(BSUM, BOFF);
  p2c_add<<<NSB, 1024, 0, stream>>>(BASE, BOFF);
  p3_scatter<<<NCH, 256, 0, stream>>>(ROW, COL, EV, BASE, STAGED);
  p4_emit<<<NB2, 256, 0, stream>>>(BASE, STAGED, EDG, RP, RP8);

  // --- MLP ---
  gemm1_kernel<<<(NN + 63) / 64, 256, 0, stream>>>(F, W1, b1, H);
  gemm2_kernel<<<(NN + 255) / 256, 256, 0, stream>>>(H, W2, b2,
                                                     (ushort4*)X0b);

  // --- propagation (bf16 x, bf16 h), column-tile paced ---
  const int tgrid = (NN * TPN + 255) / 256;
  const uint4* cur_in = X0b;
  uint4* bufs[2] = {XAb, XBb};
  for (int it = 0; it < 10; ++it) {
    uint4* o = bufs[it & 1];
    prop_kernel_bf16<<<tgrid, 256, 0, stream>>>(cur_in, o, X0b, EDG, RP,
                                                (const int4*)RP8);
    cur_in = o;
  }
  logsm_kernel<<<(NN + 255) / 256, 256, 0, stream>>>((const ushort4*)cur_in,
                                                     out);
}